// Round 5
// baseline (233.434 us; speedup 1.0000x reference)
//
#include <hip/hip_runtime.h>

// OTAM cumulative distance on MI355X (gfx950).
// Per (q,s) pair: 16x16 tile D = 1 - sim. Two banded soft-min DPs
// (forward and transposed), each result = cum[15][17]; out = -0.5*(F+T).
//
// Both DPs advance one ORIGINAL row at a time (transposed DP column jj=l+1
// consumes original row l), so the tile streams from HBM exactly once.
// State per thread: prev[18] (fwd row), S[16] (transposed col), all
// statically indexed -> registers. 3-row-deep load pipeline.

#define KSC 14.426950408889634f   // (1/lbda)*log2(e), lbda=0.1
#define CL2 0.06931471805599453f  // lbda*ln(2)

// Guaranteed single-instruction transcendentals (never libm).
#if __has_builtin(__builtin_amdgcn_exp2f)
static __device__ __forceinline__ float fexp2(float x) { return __builtin_amdgcn_exp2f(x); }
#else
static __device__ __forceinline__ float fexp2(float x) {
    float r; asm("v_exp_f32 %0, %1" : "=v"(r) : "v"(x)); return r;
}
#endif
#if __has_builtin(__builtin_amdgcn_logf)
static __device__ __forceinline__ float flog2(float x) { return __builtin_amdgcn_logf(x); }
#else
static __device__ __forceinline__ float flog2(float x) {
    float r; asm("v_log_f32 %0, %1" : "=v"(r) : "v"(x)); return r;
}
#endif

static __device__ __forceinline__ float sm2(float a, float b) {
    float mn = fminf(a, b), mx = fmaxf(a, b);
    float e  = fexp2((mn - mx) * KSC);
    return mn - CL2 * flog2(1.0f + e);
}

static __device__ __forceinline__ float sm3(float a, float b, float c) {
    float mn = fminf(fminf(a, b), c);     // -> v_min3_f32
    float s  = fexp2((mn - a) * KSC)
             + fexp2((mn - b) * KSC)
             + fexp2((mn - c) * KSC);
    return mn - CL2 * flog2(s);
}

#define UNPACK(r, b0, b1, b2, b3)                                          \
    r[0]=1.0f-b0.x;  r[1]=1.0f-b0.y;  r[2]=1.0f-b0.z;  r[3]=1.0f-b0.w;     \
    r[4]=1.0f-b1.x;  r[5]=1.0f-b1.y;  r[6]=1.0f-b1.z;  r[7]=1.0f-b1.w;     \
    r[8]=1.0f-b2.x;  r[9]=1.0f-b2.y;  r[10]=1.0f-b2.z; r[11]=1.0f-b2.w;    \
    r[12]=1.0f-b3.x; r[13]=1.0f-b3.y; r[14]=1.0f-b3.z; r[15]=1.0f-b3.w

__global__ __launch_bounds__(64) void otam_kernel(const float* __restrict__ sim,
                                                  float* __restrict__ out,
                                                  int npairs) {
    int p = blockIdx.x * 64 + threadIdx.x;
    if (p >= npairs) return;
    const float4* tp = (const float4*)(sim + (size_t)p * 256);

    float prev[18], S[16], r[16];

    // 3-row pipeline: a = row l (current), b = row l+1, c = row l+2 in flight
    float4 a0 = tp[0],  a1 = tp[1],  a2 = tp[2],  a3 = tp[3];
    float4 b0 = tp[4],  b1 = tp[5],  b2 = tp[6],  b3 = tp[7];
    float4 c0 = tp[8],  c1 = tp[9],  c2 = tp[10], c3 = tp[11];

    UNPACK(r, a0, a1, a2, a3);

    // ---- row 0 ----
    // forward DP row 0: prefix sums (padded col 17 adds 0)
    prev[0] = 0.0f;
#pragma unroll
    for (int m = 1; m <= 16; ++m) prev[m] = prev[m - 1] + r[m - 1];
    prev[17] = prev[16];

    // transposed DP column jj=1 (boundary), previous column all zeros:
    // po = 0, t = 0 for every cell
    {
        float cur = r[0];
        S[0] = cur;
#pragma unroll
        for (int i = 1; i < 16; ++i) {
            cur  = r[i] + sm3(0.0f, 0.0f, cur);
            S[i] = cur;
        }
    }

    // ---- rows 1..15 ----
    for (int l = 1; l < 16; ++l) {
        a0 = b0; a1 = b1; a2 = b2; a3 = b3;
        b0 = c0; b1 = c1; b2 = c2; b3 = c3;
        if (l + 2 < 16) {  // issue loads for row l+2
            c0 = tp[(l + 2) * 4 + 0];
            c1 = tp[(l + 2) * 4 + 1];
            c2 = tp[(l + 2) * 4 + 2];
            c3 = tp[(l + 2) * 4 + 3];
        }
        UNPACK(r, a0, a1, a2, a3);

        // forward DP row l: cum[l][m] = r[m-1] + softmin(prev[m-1], cur,
        //                       [prev[m] at boundary m==1, m==17])
        {
            float a_old = prev[0];          // == 0
            float t     = prev[1];
            float fcur  = r[0] + sm3(a_old, 0.0f, t);   // m=1 boundary (cum[l][0]=0)
            prev[1]     = fcur;
            a_old       = t;
#pragma unroll
            for (int m = 2; m <= 16; ++m) {
                t       = prev[m];
                fcur    = r[m - 1] + sm2(a_old, fcur);
                prev[m] = fcur;
                a_old   = t;
            }
            // m = 17: padded value 0, boundary
            prev[17] = sm3(a_old, fcur, prev[17]);
        }

        // transposed DP column jj = l+1 (2..16: never boundary).
        // Non-boundary cells depend ONLY on previous column -> fully parallel.
        {
            float po   = S[0];
            float scur = S[0] + r[0];
            S[0] = scur;
#pragma unroll
            for (int i = 1; i < 16; ++i) {
                float t2 = S[i];
                scur = r[i] + sm2(po, t2);
                S[i] = scur;
                po   = t2;
            }
        }
    }

    // ---- transposed DP final column jj=17 (boundary, padded data = 0) ----
    {
        float po  = S[0];
        float cur = S[0];
#pragma unroll
        for (int i = 1; i < 16; ++i) {
            float t = S[i];
            cur = sm3(po, t, cur);
            po  = t;
        }
        out[p] = -0.5f * (prev[17] + cur);
    }
}

extern "C" void kernel_launch(void* const* d_in, const int* in_sizes, int n_in,
                              void* d_out, int out_size, void* d_ws, size_t ws_size,
                              hipStream_t stream) {
    const float* sim = (const float*)d_in[0];
    float* out       = (float*)d_out;
    int npairs = in_sizes[0] / 256;            // 400*400 = 160000
    int blocks = (npairs + 63) / 64;           // 2500 single-wave blocks
    otam_kernel<<<blocks, 64, 0, stream>>>(sim, out, npairs);
}